// Round 13
// baseline (145.940 us; speedup 1.0000x reference)
//
#include <hip/hip_runtime.h>
#include <math.h>

#define Bn 4
#define Nn 512
#define Dn 64
#define Hn 8
#define TR 64          // rows per tile-block
#define NT (Nn / TR)   // 8 tiles per (b,q)
#define HS 12          // ehat_s row stride (words): 48B rows, 16B-aligned
#define PART 80        // partial floats per block: 64 PV + 8 expsum + 8 gsum

typedef float f32x4 __attribute__((ext_vector_type(4)));

// ---------------- Kernel 1: QKV projection + weight transpose -------------
__global__ __launch_bounds__(64) void qkv_kernel(
    const float* __restrict__ nin, const float* __restrict__ Wq,
    const float* __restrict__ Wk, const float* __restrict__ Wv,
    const float* __restrict__ WeG, const float* __restrict__ WgG,
    float* __restrict__ Qw, float* __restrict__ Kw, float* __restrict__ Vw,
    float* __restrict__ WeT, float* __restrict__ WgT)
{
    const int row = blockIdx.x;   // 0 .. B*N-1
    const int d = threadIdx.x;    // 0 .. 63
    if (row < Hn) {               // transpose head `row`
        WeT[row * Dn + d] = WeG[d * Hn + row];
        WgT[row * Dn + d] = WgG[d * Hn + row];
    }
    __shared__ float nrow[Dn];
    nrow[d] = nin[row * Dn + d];
    __syncthreads();
    float aq = 0.f, ak = 0.f, av = 0.f;
#pragma unroll
    for (int k = 0; k < Dn; ++k) {
        const float nv = nrow[k];
        aq = fmaf(nv, Wq[k * Dn + d], aq);
        ak = fmaf(nv, Wk[k * Dn + d], ak);
        av = fmaf(nv, Wv[k * Dn + d], av);
    }
    Qw[row * Dn + d] = aq;
    Kw[row * Dn + d] = ak;
    Vw[row * Dn + d] = av;
}

// ---------------- Kernel 2a: READ kernel ----------------------------------
// Pure read stream: e-tile -> swizzled LDS -> eb/gg/A/ehat + PV/exp/gate
// partials. Writes only 2KB raw ehat per tile, staged IN-PLACE into the
// first 2KB of this tile's eout region (cached stores; B reads it back from
// L2/L3). No big write stream -> no read/write merge hazards.
__global__ __launch_bounds__(256, 6) void stream_a(
    const float* __restrict__ e,
    const float* __restrict__ Qw, const float* __restrict__ Kw,
    const float* __restrict__ Vw,
    const float* __restrict__ WeT, const float* __restrict__ WgT,
    float* __restrict__ eout, float* __restrict__ part)
{
    const int bid  = blockIdx.x;        // bq*NT + tile
    const int bq   = bid >> 3;          // NT = 8
    const int tile = bid & 7;
    const int b    = bq >> 9;           // N = 512
    const int m0   = tile * TR;
    const int t    = threadIdx.x;       // 0..255
    const int w    = t >> 6;            // wave 0..3 = head-pair {2w,2w+1}
    const int l    = t & 63;            // lane 0..63 = row within tile

    __shared__ float e_tile[TR * Dn];               // 16384 B, swizzled slots
    __shared__ float ehat_s[TR * HS];               // 3072 B  [row][head]
    __shared__ float accb[4][Dn];                   // 1024 B
    __shared__ float ssb[Hn], gsb[Hn];              // 64 B

    // 1) e-tile loads first (HBM latency): 16KB contiguous, 4 float4/thread
    float4 st[4];
    {
        const float4* ep = (const float4*)(e + ((size_t)bq * Nn + m0) * Dn);
#pragma unroll
        for (int j = 0; j < 4; ++j) st[j] = ep[j * 256 + t];
    }

    // 2) K slice for this wave's head-pair (L2-hot) + Q (wave-uniform)
    float a0, a1;
    {
        const float4* kp = (const float4*)(Kw + ((size_t)b * Nn + m0 + l) * Dn + w * 16);
        const float4 k0 = kp[0], k1 = kp[1], k2 = kp[2], k3 = kp[3];
        const float4* qp = (const float4*)(Qw + (size_t)bq * Dn + w * 16);
        const float4 q0 = qp[0], q1 = qp[1], q2 = qp[2], q3 = qp[3];
        const float qscale = 0.35355339059327373f;  // 1/sqrt(8)
        a0 = k0.x*q0.x + k0.y*q0.y + k0.z*q0.z + k0.w*q0.w
           + k1.x*q1.x + k1.y*q1.y + k1.z*q1.z + k1.w*q1.w;
        a1 = k2.x*q2.x + k2.y*q2.y + k2.z*q2.z + k2.w*q2.w
           + k3.x*q3.x + k3.y*q3.y + k3.z*q3.z + k3.w*q3.w;
        a0 = fminf(fmaxf(a0 * qscale, -5.f), 5.f);
        a1 = fminf(fmaxf(a1 * qscale, -5.f), 5.f);
    }

    // 3) staged e -> swizzled LDS: chunk (r,g) -> slot (r, g^(r&15))
#pragma unroll
    for (int j = 0; j < 4; ++j) {
        const int c = j * 256 + t, r = c >> 4, g = c & 15;
        *(float4*)&e_tile[r * Dn + ((g ^ (r & 15)) << 2)] = st[j];
    }
    __syncthreads();

    // 4) eb/gg dots: e from swizzled LDS; weights via scalar loads (WeT/WgT,
    //    readfirstlane-uniform row pointers)
    float eb0 = 0.f, eb1 = 0.f, gg0 = 0.f, gg1 = 0.f;
    {
        const int h0 = __builtin_amdgcn_readfirstlane(2 * w);
        const float* __restrict__ we0p = WeT + h0 * Dn;
        const float* __restrict__ wg0p = WgT + h0 * Dn;
#pragma unroll
        for (int d4 = 0; d4 < 16; ++d4) {
            const float4 e4 = *(const float4*)&e_tile[l * Dn + ((d4 ^ (l & 15)) << 2)];
            const float4 A0 = *(const float4*)&we0p[d4 * 4];
            const float4 A1 = *(const float4*)&we0p[Dn + d4 * 4];
            const float4 G0 = *(const float4*)&wg0p[d4 * 4];
            const float4 G1 = *(const float4*)&wg0p[Dn + d4 * 4];
            eb0 = fmaf(e4.x, A0.x, fmaf(e4.y, A0.y, fmaf(e4.z, A0.z, fmaf(e4.w, A0.w, eb0))));
            eb1 = fmaf(e4.x, A1.x, fmaf(e4.y, A1.y, fmaf(e4.z, A1.z, fmaf(e4.w, A1.w, eb1))));
            gg0 = fmaf(e4.x, G0.x, fmaf(e4.y, G0.y, fmaf(e4.z, G0.z, fmaf(e4.w, G0.w, gg0))));
            gg1 = fmaf(e4.x, G1.x, fmaf(e4.y, G1.y, fmaf(e4.z, G1.z, fmaf(e4.w, G1.w, gg1))));
        }
    }

    // 5) ehat -> LDS [row][head] + in-place global stage (first 2KB of this
    //    tile's eout region, cached); exp/gate wave-reduce
    {
        const float eh0 = a0 + eb0, eh1 = a1 + eb1;
        float2 ehp; ehp.x = eh0; ehp.y = eh1;
        *(float2*)&ehat_s[l * HS + 2 * w] = ehp;
        float* ehg = eout + ((size_t)bq * Nn + m0) * Dn;
        *(float2*)&ehg[l * 8 + 2 * w] = ehp;
        float p0 = __expf(eh0), p1 = __expf(eh1);
        float g0 = 1.f / (1.f + __expf(-gg0));
        float g1 = 1.f / (1.f + __expf(-gg1));
#pragma unroll
        for (int off = 32; off > 0; off >>= 1) {
            p0 += __shfl_xor(p0, off, 64);
            p1 += __shfl_xor(p1, off, 64);
            g0 += __shfl_xor(g0, off, 64);
            g1 += __shfl_xor(g1, off, 64);
        }
        if (l == 0) {
            ssb[2 * w] = p0; ssb[2 * w + 1] = p1;
            gsb[2 * w] = g0; gsb[2 * w + 1] = g1;
        }
    }
    __syncthreads();   // ehat/ssb/gsb ready

    // 6) PV partials: wave w covers rows w*16..w*16+15; p = exp(ehat)
    {
        const int hc = l >> 3;
        float acc = 0.f;
        const float* vrow = Vw + ((size_t)b * Nn + m0 + w * 16) * Dn;
#pragma unroll
        for (int i = 0; i < 16; ++i) {
            const float p = __expf(ehat_s[(w * 16 + i) * HS + hc]);
            acc = fmaf(p, vrow[i * Dn + l], acc);
        }
        accb[w][l] = acc;
    }
    __syncthreads();

    // 7) fold 4 waves, emit 80-float partial
    if (w == 0) {
        const float O = accb[0][l] + accb[1][l] + accb[2][l] + accb[3][l];
        float* pb = part + (size_t)bid * PART;
        pb[l] = O;
        if (l < 8) { pb[64 + l] = ssb[l]; pb[72 + l] = gsb[l]; }
    }
}

// ---------------- Kernel 2b: WRITE kernel ---------------------------------
// Pure write stream: read this tile's 2KB staged ehat (L2/L3-hot) into LDS,
// Oe in regs, compute e_out = ehat @ Oe, nt full-line coalesced stores over
// the whole 64KB tile (including the staged 2KB). Barrier fences the
// read-before-overwrite.
__global__ __launch_bounds__(256, 8) void stream_b(
    const float* __restrict__ OeG, float* __restrict__ eout)
{
    const int bid  = blockIdx.x;        // bq*NT + tile
    const int bq   = bid >> 3;
    const int tile = bid & 7;
    const int m0   = tile * TR;
    const int t    = threadIdx.x;       // 0..255

    __shared__ float eh_lds[TR * 8];    // 2048 B

    float* ebase = eout + ((size_t)bq * Nn + m0) * Dn;

    // stage ehat tile: 2 floats/thread, coalesced 2KB
    eh_lds[t]       = ebase[t];
    eh_lds[t + 256] = ebase[t + 256];

    // Oe -> regs: thread's fixed col group cc = t&15 (L2-hot)
    const int cc = t & 15;
    f32x4 oev[Hn];
#pragma unroll
    for (int ho = 0; ho < Hn; ++ho)
        oev[ho] = *(const f32x4*)&OeG[ho * Dn + cc * 4];

    __syncthreads();   // eh_lds complete; safe to overwrite ebase

    // e_out: chunk c -> row r = c>>4; ehat row via 2x b128 LDS broadcast
#pragma unroll
    for (int j = 0; j < 4; ++j) {
        const int c = j * 256 + t, r = c >> 4;
        const float4 ehA = *(const float4*)&eh_lds[r * 8];
        const float4 ehB = *(const float4*)&eh_lds[r * 8 + 4];
        f32x4 o = oev[0] * ehA.x;
        o += oev[1] * ehA.y;
        o += oev[2] * ehA.z;
        o += oev[3] * ehA.w;
        o += oev[4] * ehB.x;
        o += oev[5] * ehB.y;
        o += oev[6] * ehB.z;
        o += oev[7] * ehB.w;
        __builtin_nontemporal_store(o, (f32x4*)ebase + c);
    }
}

// ---------------- Kernel 3: fold partials -> n_out ------------------------
__global__ __launch_bounds__(64) void reduce_kernel(
    const float* __restrict__ part, const float* __restrict__ WoG,
    float* __restrict__ nout)
{
    const int bq = blockIdx.x;
    const int l  = threadIdx.x;
    const int h  = l >> 3;
    const float* pb = part + (size_t)bq * NT * PART;
    float O = 0.f, S = 0.f, G = 0.f;
#pragma unroll
    for (int tl = 0; tl < NT; ++tl) {
        O += pb[tl * PART + l];
        S += pb[tl * PART + 64 + h];
        G += pb[tl * PART + 72 + h];
    }
    __shared__ float vo_s[Dn];
    vo_s[l] = (O / S) * log1pf(G);
    __syncthreads();
    float a = 0.f;
#pragma unroll
    for (int k = 0; k < Dn; ++k)
        a = fmaf(vo_s[k], WoG[k * Dn + l], a);
    nout[(size_t)bq * Dn + l] = a;
}

// ---------------- Host launcher -------------------------------------------
extern "C" void kernel_launch(void* const* d_in, const int* in_sizes, int n_in,
                              void* d_out, int out_size, void* d_ws, size_t ws_size,
                              hipStream_t stream)
{
    (void)in_sizes; (void)n_in; (void)out_size; (void)ws_size;
    const float* nin = (const float*)d_in[0];
    const float* e   = (const float*)d_in[1];
    const float* Wq  = (const float*)d_in[2];
    const float* Wk  = (const float*)d_in[3];
    const float* Wv  = (const float*)d_in[4];
    const float* Wo  = (const float*)d_in[5];
    const float* Wg  = (const float*)d_in[6];
    const float* We  = (const float*)d_in[7];
    const float* Oe  = (const float*)d_in[8];

    float* Qw   = (float*)d_ws;               // B*N*D floats
    float* Kw   = Qw + Bn * Nn * Dn;
    float* Vw   = Kw + Bn * Nn * Dn;
    float* part = Vw + Bn * Nn * Dn;          // B*N*NT*PART floats (5.2 MB)
    float* WeT  = part + (size_t)Bn * Nn * NT * PART;   // 512 floats
    float* WgT  = WeT + Hn * Dn;                        // 512 floats

    float* nout = (float*)d_out;              // B*N*D floats
    float* eout = nout + Bn * Nn * Dn;        // B*N*N*D floats

    qkv_kernel<<<Bn * Nn, 64, 0, stream>>>(nin, Wq, Wk, Wv, We, Wg,
                                           Qw, Kw, Vw, WeT, WgT);
    stream_a<<<Bn * Nn * NT, 256, 0, stream>>>(e, Qw, Kw, Vw, WeT, WgT,
                                               eout, part);
    stream_b<<<Bn * Nn * NT, 256, 0, stream>>>(Oe, eout);
    reduce_kernel<<<Bn * Nn, 64, 0, stream>>>(part, Wo, nout);
}

// Round 14
// 133.412 us; speedup vs baseline: 1.0939x; 1.0939x over previous
//
#include <hip/hip_runtime.h>
#include <math.h>

#define Bn 4
#define Nn 512
#define Dn 64
#define Hn 8
#define TR 64          // rows per tile-block
#define NT (Nn / TR)   // 8 tiles per (b,q)
#define HS 12          // ehat row stride (words): 48B rows, 16B-aligned
#define PART 80        // partial floats per block: 64 PV + 8 expsum + 8 gsum

typedef float f32x4 __attribute__((ext_vector_type(4)));

// ---------------- Kernel 1: QKV projection -------------------------------
__global__ __launch_bounds__(64) void qkv_kernel(
    const float* __restrict__ nin, const float* __restrict__ Wq,
    const float* __restrict__ Wk, const float* __restrict__ Wv,
    float* __restrict__ Qw, float* __restrict__ Kw, float* __restrict__ Vw)
{
    const int row = blockIdx.x;   // 0 .. B*N-1
    const int d = threadIdx.x;    // 0 .. 63
    __shared__ float nrow[Dn];
    nrow[d] = nin[row * Dn + d];
    __syncthreads();
    float aq = 0.f, ak = 0.f, av = 0.f;
#pragma unroll
    for (int k = 0; k < Dn; ++k) {
        const float nv = nrow[k];
        aq = fmaf(nv, Wq[k * Dn + d], aq);
        ak = fmaf(nv, Wk[k * Dn + d], ak);
        av = fmaf(nv, Wv[k * Dn + d], av);
    }
    Qw[row * Dn + d] = aq;
    Kw[row * Dn + d] = ak;
    Vw[row * Dn + d] = av;
}

// ---------------- Kernel 2: streaming tile kernel -------------------------
// R6-nt structure (reg-staged coalesced e-read -> XOR-swizzled LDS tile,
// LDS weights, nt coalesced e_out stores) with the instruction stream cut:
//  - phase-5 dots use f32x4 vector accumulators -> v_pk_fma_f32 (2x f32 per
//    instr): 256 -> 128 FMA instructions per thread.
//  - Oe in 8xfloat4 VGPRs (col group cc = t&15 fixed across chunks).
//  - ehat stored [row][HS=12]: 1 float2 write + 2 b128 broadcast reads.
__global__ __launch_bounds__(256, 6) void stream_kernel(
    const float* __restrict__ e,
    const float* __restrict__ Qw, const float* __restrict__ Kw,
    const float* __restrict__ Vw,
    const float* __restrict__ WeG, const float* __restrict__ WgG,
    const float* __restrict__ OeG,
    float* __restrict__ eout, float* __restrict__ part)
{
    const int bid  = blockIdx.x;        // bq*NT + tile
    const int bq   = bid >> 3;          // NT = 8
    const int tile = bid & 7;
    const int b    = bq >> 9;           // N = 512
    const int m0   = tile * TR;
    const int t    = threadIdx.x;       // 0..255
    const int w    = t >> 6;            // wave 0..3 = head-pair {2w,2w+1}
    const int l    = t & 63;            // lane 0..63 = row within tile

    __shared__ float e_tile[TR * Dn];               // 16384 B, swizzled slots
    __shared__ float ehat_s[TR * HS];               // 3072 B  [row][head]
    __shared__ __align__(16) float we_s[Hn][Dn];    // 2048 B
    __shared__ __align__(16) float wg_s[Hn][Dn];    // 2048 B
    __shared__ float accb[4][Dn];                   // 1024 B
    __shared__ float ssb[Hn], gsb[Hn];              // 64 B

    // 1) e-tile loads first (HBM latency): 16KB contiguous, 4 float4/thread
    float4 st[4];
    {
        const float4* ep = (const float4*)(e + ((size_t)bq * Nn + m0) * Dn);
#pragma unroll
        for (int j = 0; j < 4; ++j) st[j] = ep[j * 256 + t];
    }

    // 2) K slice for this wave's head-pair (L2-hot) + Q (wave-uniform)
    float a0, a1;
    {
        const float4* kp = (const float4*)(Kw + ((size_t)b * Nn + m0 + l) * Dn + w * 16);
        const float4 k0 = kp[0], k1 = kp[1], k2 = kp[2], k3 = kp[3];
        const float4* qp = (const float4*)(Qw + (size_t)bq * Dn + w * 16);
        const float4 q0 = qp[0], q1 = qp[1], q2 = qp[2], q3 = qp[3];
        const float qscale = 0.35355339059327373f;  // 1/sqrt(8)
        a0 = k0.x*q0.x + k0.y*q0.y + k0.z*q0.z + k0.w*q0.w
           + k1.x*q1.x + k1.y*q1.y + k1.z*q1.z + k1.w*q1.w;
        a1 = k2.x*q2.x + k2.y*q2.y + k2.z*q2.z + k2.w*q2.w
           + k3.x*q3.x + k3.y*q3.y + k3.z*q3.z + k3.w*q3.w;
        a0 = fminf(fmaxf(a0 * qscale, -5.f), 5.f);
        a1 = fminf(fmaxf(a1 * qscale, -5.f), 5.f);
    }

    // 3) weights (L2-hot). We/Wg (D,H) -> LDS [h][d] transpose.
    for (int i = t; i < Dn * Hn; i += 256) {
        const int d = i >> 3, h = i & 7;
        we_s[h][d] = WeG[i];
        wg_s[h][d] = WgG[i];
    }

    // 4) staged e -> swizzled LDS: chunk (r,g) -> slot (r, g^(r&15))
#pragma unroll
    for (int j = 0; j < 4; ++j) {
        const int c = j * 256 + t, r = c >> 4, g = c & 15;
        *(float4*)&e_tile[r * Dn + ((g ^ (r & 15)) << 2)] = st[j];
    }

    // 5) Oe -> registers (st[] dead): fixed col group cc = t&15, L2-hot
    const int cc = t & 15;
    f32x4 oev[Hn];
#pragma unroll
    for (int ho = 0; ho < Hn; ++ho)
        oev[ho] = *(const f32x4*)&OeG[ho * Dn + cc * 4];

    __syncthreads();

    // 6) eb/gg dots with f32x4 vector accumulators (v_pk_fma_f32 path)
    f32x4 veb0 = {0,0,0,0}, veb1 = {0,0,0,0};
    f32x4 vgg0 = {0,0,0,0}, vgg1 = {0,0,0,0};
    {
        const f32x4* we0 = (const f32x4*)we_s[2 * w];
        const f32x4* we1 = (const f32x4*)we_s[2 * w + 1];
        const f32x4* wg0 = (const f32x4*)wg_s[2 * w];
        const f32x4* wg1 = (const f32x4*)wg_s[2 * w + 1];
#pragma unroll
        for (int d4 = 0; d4 < 16; ++d4) {
            const f32x4 e4 = *(const f32x4*)&e_tile[l * Dn + ((d4 ^ (l & 15)) << 2)];
            veb0 += e4 * we0[d4];
            veb1 += e4 * we1[d4];
            vgg0 += e4 * wg0[d4];
            vgg1 += e4 * wg1[d4];
        }
    }
    const float eb0 = veb0.x + veb0.y + veb0.z + veb0.w;
    const float eb1 = veb1.x + veb1.y + veb1.z + veb1.w;
    const float gg0 = vgg0.x + vgg0.y + vgg0.z + vgg0.w;
    const float gg1 = vgg1.x + vgg1.y + vgg1.z + vgg1.w;

    // 7) ehat -> LDS [row][head] (one float2/thread); exp/gate wave-reduce
    {
        const float eh0 = a0 + eb0, eh1 = a1 + eb1;
        float2 ehp; ehp.x = eh0; ehp.y = eh1;
        *(float2*)&ehat_s[l * HS + 2 * w] = ehp;
        float p0 = __expf(eh0), p1 = __expf(eh1);
        float g0 = 1.f / (1.f + __expf(-gg0));
        float g1 = 1.f / (1.f + __expf(-gg1));
#pragma unroll
        for (int off = 32; off > 0; off >>= 1) {
            p0 += __shfl_xor(p0, off, 64);
            p1 += __shfl_xor(p1, off, 64);
            g0 += __shfl_xor(g0, off, 64);
            g1 += __shfl_xor(g1, off, 64);
        }
        if (l == 0) {
            ssb[2 * w] = p0; ssb[2 * w + 1] = p1;
            gsb[2 * w] = g0; gsb[2 * w + 1] = g1;
        }
    }
    __syncthreads();   // ehat/ssb/gsb ready; e_tile reads done

    // 8) e_out: chunk c -> row r = c>>4, fixed col group cc; ehat row via
    //    2x b128 broadcast; Oe from regs; nt full-line coalesced stores
    {
        float4* eo = (float4*)(eout + ((size_t)bq * Nn + m0) * Dn);
#pragma unroll
        for (int j = 0; j < 4; ++j) {
            const int c = j * 256 + t, r = c >> 4;
            const float4 ehA = *(const float4*)&ehat_s[r * HS];
            const float4 ehB = *(const float4*)&ehat_s[r * HS + 4];
            f32x4 o = oev[0] * ehA.x;
            o += oev[1] * ehA.y;
            o += oev[2] * ehA.z;
            o += oev[3] * ehA.w;
            o += oev[4] * ehB.x;
            o += oev[5] * ehB.y;
            o += oev[6] * ehB.z;
            o += oev[7] * ehB.w;
            __builtin_nontemporal_store(o, (f32x4*)eo + c);
        }
    }

    // 9) PV partials: wave w covers rows w*16..w*16+15; p = exp(ehat)
    {
        const int hc = l >> 3;
        float acc = 0.f;
        const float* vrow = Vw + ((size_t)b * Nn + m0 + w * 16) * Dn;
#pragma unroll
        for (int i = 0; i < 16; ++i) {
            const float p = __expf(ehat_s[(w * 16 + i) * HS + hc]);
            acc = fmaf(p, vrow[i * Dn + l], acc);
        }
        accb[w][l] = acc;
    }
    __syncthreads();

    // 10) fold 4 waves, emit 80-float partial
    if (w == 0) {
        const float O = accb[0][l] + accb[1][l] + accb[2][l] + accb[3][l];
        float* pb = part + (size_t)bid * PART;
        pb[l] = O;
        if (l < 8) { pb[64 + l] = ssb[l]; pb[72 + l] = gsb[l]; }
    }
}

// ---------------- Kernel 3: fold partials -> n_out ------------------------
__global__ __launch_bounds__(64) void reduce_kernel(
    const float* __restrict__ part, const float* __restrict__ WoG,
    float* __restrict__ nout)
{
    const int bq = blockIdx.x;
    const int l  = threadIdx.x;
    const int h  = l >> 3;
    const float* pb = part + (size_t)bq * NT * PART;
    float O = 0.f, S = 0.f, G = 0.f;
#pragma unroll
    for (int tl = 0; tl < NT; ++tl) {
        O += pb[tl * PART + l];
        S += pb[tl * PART + 64 + h];
        G += pb[tl * PART + 72 + h];
    }
    __shared__ float vo_s[Dn];
    vo_s[l] = (O / S) * log1pf(G);
    __syncthreads();
    float a = 0.f;
#pragma unroll
    for (int k = 0; k < Dn; ++k)
        a = fmaf(vo_s[k], WoG[k * Dn + l], a);
    nout[(size_t)bq * Dn + l] = a;
}

// ---------------- Host launcher -------------------------------------------
extern "C" void kernel_launch(void* const* d_in, const int* in_sizes, int n_in,
                              void* d_out, int out_size, void* d_ws, size_t ws_size,
                              hipStream_t stream)
{
    (void)in_sizes; (void)n_in; (void)out_size; (void)ws_size;
    const float* nin = (const float*)d_in[0];
    const float* e   = (const float*)d_in[1];
    const float* Wq  = (const float*)d_in[2];
    const float* Wk  = (const float*)d_in[3];
    const float* Wv  = (const float*)d_in[4];
    const float* Wo  = (const float*)d_in[5];
    const float* Wg  = (const float*)d_in[6];
    const float* We  = (const float*)d_in[7];
    const float* Oe  = (const float*)d_in[8];

    float* Qw   = (float*)d_ws;               // B*N*D floats
    float* Kw   = Qw + Bn * Nn * Dn;
    float* Vw   = Kw + Bn * Nn * Dn;
    float* part = Vw + Bn * Nn * Dn;          // B*N*NT*PART floats (5.2 MB)

    float* nout = (float*)d_out;              // B*N*D floats
    float* eout = nout + Bn * Nn * Dn;        // B*N*N*D floats

    qkv_kernel<<<Bn * Nn, 64, 0, stream>>>(nin, Wq, Wk, Wv, Qw, Kw, Vw);
    stream_kernel<<<Bn * Nn * NT, 256, 0, stream>>>(e, Qw, Kw, Vw, We, Wg,
                                                    Oe, eout, part);
    reduce_kernel<<<Bn * Nn, 64, 0, stream>>>(part, Wo, nout);
}